// Round 1
// baseline (215.759 us; speedup 1.0000x reference)
//
#include <hip/hip_runtime.h>
#include <hip/hip_bf16.h>
#include <stdint.h>

#define S_LEN 1024
#define BATCH 64
#define HDIM  1024
#define VOCAB 50257

using f32x4 = __attribute__((ext_vector_type(4))) float;
using bfx8  = __attribute__((ext_vector_type(8))) short;
using bfx4  = __attribute__((ext_vector_type(4))) short;

__device__ __forceinline__ short f2bf(float f) {
  uint32_t u = __float_as_uint(f);
  u += 0x7fffu + ((u >> 16) & 1u);   // round-to-nearest-even
  return (short)(u >> 16);
}

// ---------------- prep: xh_bf16 = [embed[seq[b]] | h0[b]] ----------------
__global__ __launch_bounds__(256) void k_prep(const int* __restrict__ seq,
                                              const float* __restrict__ embed,
                                              const float* __restrict__ h0,
                                              short* __restrict__ xh) {
  int b = blockIdx.x >> 1, half = blockIdx.x & 1;
  int k = threadIdx.x * 4;
  const float* src = half ? (h0 + (size_t)b * HDIM + k)
                          : (embed + (size_t)seq[b] * HDIM + k);
  f32x4 v = *(const f32x4*)src;
  bfx4 o;
  o[0] = f2bf(v[0]); o[1] = f2bf(v[1]); o[2] = f2bf(v[2]); o[3] = f2bf(v[3]);
  *(bfx4*)(xh + (size_t)b * 2048 + half * HDIM + k) = o;
}

// ---------------- u_e[k] = sum_h v[h] * Wa[h][HDIM + k]  (atomic partials) ----
__global__ __launch_bounds__(256) void k_ue(const float* __restrict__ v,
                                            const float* __restrict__ Wa,
                                            float* __restrict__ ue) {
  int kb = blockIdx.x & 3, hc = blockIdx.x >> 2;
  int k = kb * 256 + threadIdx.x;
  int h0 = hc * 64;
  float acc = 0.f;
  #pragma unroll 8
  for (int i = 0; i < 64; ++i)
    acc += v[h0 + i] * Wa[(size_t)(h0 + i) * 2048 + HDIM + k];
  atomicAdd(&ue[k], acc);
}

// ---------------- generic tall GEMM partial: part[sl][r][b] over K-slice -----
// A row r, global k:  k < ksplit ? A0[r*lda + k] : A1[r*lda + k - ksplit]
__global__ __launch_bounds__(256) void k_mfma_part(const float* __restrict__ A0,
                                                   const float* __restrict__ A1,
                                                   int lda, int ksplit,
                                                   const short* __restrict__ X,
                                                   int Ktot, int kslice,
                                                   float* __restrict__ part, int M) {
  int w = threadIdx.x >> 6, lane = threadIdx.x & 63;
  int r_lo = lane & 15, kq = (lane >> 4) * 8;
  int r0 = blockIdx.x * 64 + w * 16;
  int row = r0 + r_lo;
  const float* a0r = A0 + (size_t)row * lda;
  const float* a1r = A1 + (size_t)row * lda - ksplit;
  const short* x0 = X + (size_t)(r_lo) * Ktot;
  const short* x1 = X + (size_t)(16 + r_lo) * Ktot;
  const short* x2 = X + (size_t)(32 + r_lo) * Ktot;
  const short* x3 = X + (size_t)(48 + r_lo) * Ktot;
  int kbeg = blockIdx.y * kslice, kend = kbeg + kslice;
  f32x4 acc0 = {0,0,0,0}, acc1 = {0,0,0,0}, acc2 = {0,0,0,0}, acc3 = {0,0,0,0};
  #pragma unroll 4
  for (int k0 = kbeg; k0 < kend; k0 += 32) {
    int k = k0 + kq;
    const float* ap = (k < ksplit) ? (a0r + k) : (a1r + k);
    f32x4 a0 = *(const f32x4*)ap;
    f32x4 a1 = *(const f32x4*)(ap + 4);
    bfx8 af;
    af[0] = f2bf(a0[0]); af[1] = f2bf(a0[1]); af[2] = f2bf(a0[2]); af[3] = f2bf(a0[3]);
    af[4] = f2bf(a1[0]); af[5] = f2bf(a1[1]); af[6] = f2bf(a1[2]); af[7] = f2bf(a1[3]);
    bfx8 b0 = *(const bfx8*)(x0 + k);
    bfx8 b1 = *(const bfx8*)(x1 + k);
    bfx8 b2 = *(const bfx8*)(x2 + k);
    bfx8 b3 = *(const bfx8*)(x3 + k);
    acc0 = __builtin_amdgcn_mfma_f32_16x16x32_bf16(af, b0, acc0, 0, 0, 0);
    acc1 = __builtin_amdgcn_mfma_f32_16x16x32_bf16(af, b1, acc1, 0, 0, 0);
    acc2 = __builtin_amdgcn_mfma_f32_16x16x32_bf16(af, b2, acc2, 0, 0, 0);
    acc3 = __builtin_amdgcn_mfma_f32_16x16x32_bf16(af, b3, acc3, 0, 0, 0);
  }
  int rw = r0 + 4 * (lane >> 4);
  size_t base = (size_t)blockIdx.y * M * 64;
  #pragma unroll
  for (int i = 0; i < 4; ++i) {
    float* p = part + base + (size_t)(rw + i) * 64;
    p[ 0 + r_lo] = acc0[i];
    p[16 + r_lo] = acc1[i];
    p[32 + r_lo] = acc2[i];
    p[48 + r_lo] = acc3[i];
  }
}

// ---------------- LSTM pointwise: combine gate partials -> h, c, xc[:H] ------
__global__ __launch_bounds__(256) void k_lstm_pw(const float* __restrict__ part,
                                                 const float* __restrict__ b_ih,
                                                 const float* __restrict__ b_hh,
                                                 const float* __restrict__ c0,
                                                 float* __restrict__ out_h,
                                                 float* __restrict__ out_c,
                                                 short* __restrict__ xc) {
  int t = blockIdx.x * 256 + threadIdx.x;
  int b = t & 63, hi = t >> 6;
  float g[4];
  #pragma unroll
  for (int ty = 0; ty < 4; ++ty) {
    int r = ty * HDIM + hi;
    float s = b_ih[r] + b_hh[r];
    #pragma unroll
    for (int sl = 0; sl < 4; ++sl) s += part[((size_t)sl * 4096 + r) * 64 + b];
    g[ty] = s;
  }
  float ig = 1.f / (1.f + __expf(-g[0]));
  float fg = 1.f / (1.f + __expf(-g[1]));
  float gg = tanhf(g[2]);
  float og = 1.f / (1.f + __expf(-g[3]));
  float c = fg * c0[(size_t)b * HDIM + hi] + ig * gg;
  float h = og * tanhf(c);
  out_h[(size_t)b * HDIM + hi] = h;
  out_c[(size_t)b * HDIM + hi] = c;
  xc[(size_t)b * 2048 + hi] = f2bf(h);
}

// ---------------- single pass over enc: energies + online-softmax ctx partials
__global__ __launch_bounds__(256) void k_attn(const float* __restrict__ enc,
                                              const float* __restrict__ ue,
                                              float* __restrict__ e_ws,
                                              float* __restrict__ ctx_part,
                                              float* __restrict__ ml_ws) {
  int b = blockIdx.x & 63, ch = blockIdx.x >> 6;
  int w = threadIdx.x >> 6, lane = threadIdx.x & 63;
  f32x4 uev[4];
  #pragma unroll
  for (int j = 0; j < 4; ++j) uev[j] = *(const f32x4*)(ue + j * 256 + lane * 4);
  float m = -3.0e38f, l = 0.f;
  f32x4 cacc[4] = {{0,0,0,0},{0,0,0,0},{0,0,0,0},{0,0,0,0}};
  int sbase = ch * 64 + w * 16;
  for (int i = 0; i < 16; ++i) {
    int s = sbase + i;
    const float* ep = enc + ((size_t)s * BATCH + b) * HDIM;
    f32x4 ev[4];
    #pragma unroll
    for (int j = 0; j < 4; ++j) ev[j] = *(const f32x4*)(ep + j * 256 + lane * 4);
    float d = 0.f;
    #pragma unroll
    for (int j = 0; j < 4; ++j)
      d += ev[j][0]*uev[j][0] + ev[j][1]*uev[j][1] + ev[j][2]*uev[j][2] + ev[j][3]*uev[j][3];
    #pragma unroll
    for (int off = 32; off >= 1; off >>= 1) d += __shfl_xor(d, off);
    if (lane == 0) e_ws[(size_t)b * S_LEN + s] = d;
    float mn = fmaxf(m, d);
    float sc = __expf(m - mn);
    float p  = __expf(d - mn);
    l = l * sc + p;
    #pragma unroll
    for (int j = 0; j < 4; ++j) cacc[j] = cacc[j] * sc + p * ev[j];
    m = mn;
  }
  __shared__ float ls_ctx[4][1024];
  __shared__ float ls_m[4], ls_l[4];
  #pragma unroll
  for (int j = 0; j < 4; ++j) *(f32x4*)&ls_ctx[w][j * 256 + lane * 4] = cacc[j];
  if (lane == 0) { ls_m[w] = m; ls_l[w] = l; }
  __syncthreads();
  float mb = fmaxf(fmaxf(ls_m[0], ls_m[1]), fmaxf(ls_m[2], ls_m[3]));
  float f0 = __expf(ls_m[0] - mb), f1 = __expf(ls_m[1] - mb);
  float f2 = __expf(ls_m[2] - mb), f3 = __expf(ls_m[3] - mb);
  float lb = ls_l[0]*f0 + ls_l[1]*f1 + ls_l[2]*f2 + ls_l[3]*f3;
  int h = threadIdx.x * 4;
  f32x4 v0 = *(f32x4*)&ls_ctx[0][h];
  f32x4 v1 = *(f32x4*)&ls_ctx[1][h];
  f32x4 v2 = *(f32x4*)&ls_ctx[2][h];
  f32x4 v3 = *(f32x4*)&ls_ctx[3][h];
  f32x4 sum = f0*v0 + f1*v1 + f2*v2 + f3*v3;
  *(f32x4*)(ctx_part + (size_t)(b * 16 + ch) * HDIM + h) = sum;
  if (threadIdx.x == 0) {
    ml_ws[(b * 16 + ch) * 2 + 0] = mb;
    ml_ws[(b * 16 + ch) * 2 + 1] = lb;
  }
}

// ---------------- combine chunk partials -> attn out + ctx (bf16 into xc[H:]) -
__global__ __launch_bounds__(256) void k_attn_comb(const float* __restrict__ e_ws,
                                                   const float* __restrict__ ctx_part,
                                                   const float* __restrict__ ml_ws,
                                                   float* __restrict__ attn_out,
                                                   short* __restrict__ xc) {
  int b = blockIdx.x;
  float mc[16], lc[16], fc[16];
  float mb = -3.0e38f;
  #pragma unroll
  for (int c = 0; c < 16; ++c) {
    mc[c] = ml_ws[(b * 16 + c) * 2 + 0];
    lc[c] = ml_ws[(b * 16 + c) * 2 + 1];
    mb = fmaxf(mb, mc[c]);
  }
  float L = 0.f;
  #pragma unroll
  for (int c = 0; c < 16; ++c) { fc[c] = __expf(mc[c] - mb); L += lc[c] * fc[c]; }
  float invL = 1.f / L;
  int h = threadIdx.x * 4;
  f32x4 sum = {0,0,0,0};
  #pragma unroll
  for (int c = 0; c < 16; ++c) {
    f32x4 vv = *(const f32x4*)(ctx_part + (size_t)(b * 16 + c) * HDIM + h);
    sum += fc[c] * vv;
  }
  sum *= invL;
  bfx4 o;
  o[0] = f2bf(sum[0]); o[1] = f2bf(sum[1]); o[2] = f2bf(sum[2]); o[3] = f2bf(sum[3]);
  *(bfx4*)(xc + (size_t)b * 2048 + HDIM + h) = o;
  int s = threadIdx.x * 4;
  f32x4 ev = *(const f32x4*)(e_ws + (size_t)b * S_LEN + s);
  f32x4 a;
  a[0] = __expf(ev[0] - mb) * invL; a[1] = __expf(ev[1] - mb) * invL;
  a[2] = __expf(ev[2] - mb) * invL; a[3] = __expf(ev[3] - mb) * invL;
  *(f32x4*)(attn_out + (size_t)b * S_LEN + s) = a;
}

// ---------------- tmp = tanh(sum partials + bal) -> bf16 ---------------------
__global__ __launch_bounds__(256) void k_tmp_comb(const float* __restrict__ part,
                                                  const float* __restrict__ bal,
                                                  short* __restrict__ tmpb) {
  int t = blockIdx.x * 256 + threadIdx.x;
  int b = t & 63, j = t >> 6;
  float s = bal[j];
  #pragma unroll
  for (int sl = 0; sl < 4; ++sl) s += part[((size_t)sl * HDIM + j) * 64 + b];
  tmpb[(size_t)b * HDIM + j] = f2bf(tanhf(s));
}

// ---------------- logits = tmp @ Wout^T + bout  (MFMA, direct write) ---------
__global__ __launch_bounds__(256) void k_logits(const float* __restrict__ Wout,
                                                const short* __restrict__ tmpb,
                                                const float* __restrict__ bout,
                                                float* __restrict__ out) {
  int w = threadIdx.x >> 6, lane = threadIdx.x & 63;
  int r_lo = lane & 15, kq = (lane >> 4) * 8;
  int v0 = blockIdx.x * 64;
  int row = v0 + w * 16 + r_lo;
  if (row >= VOCAB) row = VOCAB - 1;
  const float* ar = Wout + (size_t)row * HDIM;
  const short* x0 = tmpb + (size_t)(r_lo) * HDIM;
  const short* x1 = tmpb + (size_t)(16 + r_lo) * HDIM;
  const short* x2 = tmpb + (size_t)(32 + r_lo) * HDIM;
  const short* x3 = tmpb + (size_t)(48 + r_lo) * HDIM;
  f32x4 acc0 = {0,0,0,0}, acc1 = {0,0,0,0}, acc2 = {0,0,0,0}, acc3 = {0,0,0,0};
  #pragma unroll 4
  for (int k0 = 0; k0 < HDIM; k0 += 32) {
    int k = k0 + kq;
    f32x4 a0 = *(const f32x4*)(ar + k);
    f32x4 a1 = *(const f32x4*)(ar + k + 4);
    bfx8 af;
    af[0] = f2bf(a0[0]); af[1] = f2bf(a0[1]); af[2] = f2bf(a0[2]); af[3] = f2bf(a0[3]);
    af[4] = f2bf(a1[0]); af[5] = f2bf(a1[1]); af[6] = f2bf(a1[2]); af[7] = f2bf(a1[3]);
    bfx8 b0 = *(const bfx8*)(x0 + k);
    bfx8 b1 = *(const bfx8*)(x1 + k);
    bfx8 b2 = *(const bfx8*)(x2 + k);
    bfx8 b3 = *(const bfx8*)(x3 + k);
    acc0 = __builtin_amdgcn_mfma_f32_16x16x32_bf16(af, b0, acc0, 0, 0, 0);
    acc1 = __builtin_amdgcn_mfma_f32_16x16x32_bf16(af, b1, acc1, 0, 0, 0);
    acc2 = __builtin_amdgcn_mfma_f32_16x16x32_bf16(af, b2, acc2, 0, 0, 0);
    acc3 = __builtin_amdgcn_mfma_f32_16x16x32_bf16(af, b3, acc3, 0, 0, 0);
  }
  __shared__ float lt[64][65];
  int rw4 = w * 16 + 4 * (lane >> 4);
  #pragma unroll
  for (int i = 0; i < 4; ++i) {
    lt[ 0 + r_lo][rw4 + i] = acc0[i];
    lt[16 + r_lo][rw4 + i] = acc1[i];
    lt[32 + r_lo][rw4 + i] = acc2[i];
    lt[48 + r_lo][rw4 + i] = acc3[i];
  }
  __syncthreads();
  int vloc = threadIdx.x & 63, bq = threadIdx.x >> 6;
  int v = v0 + vloc;
  if (v < VOCAB) {
    float bo = bout[v];
    #pragma unroll
    for (int q = 0; q < 16; ++q) {
      int b = bq * 16 + q;
      out[(size_t)b * VOCAB + v] = lt[b][vloc] + bo;
    }
  }
}

extern "C" void kernel_launch(void* const* d_in, const int* in_sizes, int n_in,
                              void* d_out, int out_size, void* d_ws, size_t ws_size,
                              hipStream_t stream) {
  const float* enc   = (const float*)d_in[0];
  const int*   seq   = (const int*)  d_in[1];
  const float* h0    = (const float*)d_in[2];
  const float* c0    = (const float*)d_in[3];
  const float* embed = (const float*)d_in[4];
  const float* W_ih  = (const float*)d_in[5];
  const float* W_hh  = (const float*)d_in[6];
  const float* b_ih  = (const float*)d_in[7];
  const float* b_hh  = (const float*)d_in[8];
  const float* Wa    = (const float*)d_in[9];
  // d_in[10] = ba: cancels in softmax, unused
  const float* vvec  = (const float*)d_in[11];
  const float* Wal   = (const float*)d_in[12];
  const float* bal   = (const float*)d_in[13];
  const float* Wout  = (const float*)d_in[14];
  const float* bout  = (const float*)d_in[15];

  float* out        = (float*)d_out;
  float* out_h      = out + (size_t)BATCH * VOCAB;
  float* out_c      = out_h + BATCH * HDIM;
  float* out_attn   = out_c + BATCH * HDIM;

  float* ws         = (float*)d_ws;
  float* ue         = ws;                          // 1024
  float* e_ws       = ue + 1024;                   // 64*1024
  float* ml_ws      = e_ws + 64 * 1024;            // 64*16*2
  float* ctx_part   = ml_ws + 2048;                // 64*16*1024
  float* gates_part = ctx_part + 64 * 16 * 1024;   // 4*4096*64
  float* tmp_part   = gates_part + 4 * 4096 * 64;  // 4*1024*64
  short* xh         = (short*)(tmp_part + 4 * 1024 * 64);  // 64*2048 bf16
  short* xc         = xh + 64 * 2048;              // 64*2048 bf16
  short* tmpb       = xc + 64 * 2048;              // 64*1024 bf16

  hipMemsetAsync(ue, 0, 1024 * sizeof(float), stream);
  k_prep<<<128, 256, 0, stream>>>(seq, embed, h0, xh);
  k_ue<<<64, 256, 0, stream>>>(vvec, Wa, ue);
  k_mfma_part<<<dim3(64, 4), 256, 0, stream>>>(W_ih, W_hh, 1024, 1024, xh, 2048, 512,
                                               gates_part, 4096);
  k_lstm_pw<<<256, 256, 0, stream>>>(gates_part, b_ih, b_hh, c0, out_h, out_c, xc);
  k_attn<<<1024, 256, 0, stream>>>(enc, ue, e_ws, ctx_part, ml_ws);
  k_attn_comb<<<64, 256, 0, stream>>>(e_ws, ctx_part, ml_ws, out_attn, xc);
  k_mfma_part<<<dim3(16, 4), 256, 0, stream>>>(Wal, Wal, 2048, 2048, xc, 2048, 512,
                                               tmp_part, 1024);
  k_tmp_comb<<<256, 256, 0, stream>>>(tmp_part, bal, tmpb);
  k_logits<<<786, 256, 0, stream>>>(Wout, tmpb, bout, out);
}

// Round 2
// 206.132 us; speedup vs baseline: 1.0467x; 1.0467x over previous
//
#include <hip/hip_runtime.h>
#include <hip/hip_bf16.h>
#include <stdint.h>

#define S_LEN 1024
#define BATCH 64
#define HDIM  1024
#define VOCAB 50257

using f32x4 = __attribute__((ext_vector_type(4))) float;
using bfx8  = __attribute__((ext_vector_type(8))) short;
using bfx4  = __attribute__((ext_vector_type(4))) short;

__device__ __forceinline__ short f2bf(float f) {
  uint32_t u = __float_as_uint(f);
  u += 0x7fffu + ((u >> 16) & 1u);   // round-to-nearest-even
  return (short)(u >> 16);
}

__device__ __forceinline__ float sigmf(float x) {
  return 1.f / (1.f + __expf(-x));
}

// ===== L1: bid<128: xh = [embed[seq[b]] | h0[b]] bf16 ; bid>=128: ue partials
__global__ __launch_bounds__(256) void k_prep(const int* __restrict__ seq,
                                              const float* __restrict__ embed,
                                              const float* __restrict__ h0,
                                              const float* __restrict__ Wa,
                                              const float* __restrict__ vvec,
                                              short* __restrict__ xh,
                                              float* __restrict__ ue_part) {
  int bid = blockIdx.x;
  if (bid < 128) {
    int b = bid >> 1, half = bid & 1;
    int k = threadIdx.x * 4;
    const float* src = half ? (h0 + (size_t)b * HDIM + k)
                            : (embed + (size_t)seq[b] * HDIM + k);
    f32x4 v = *(const f32x4*)src;
    bfx4 o;
    o[0] = f2bf(v[0]); o[1] = f2bf(v[1]); o[2] = f2bf(v[2]); o[3] = f2bf(v[3]);
    *(bfx4*)(xh + (size_t)b * 2048 + half * HDIM + k) = o;
  } else {
    // ue_part[c][k] = sum over 64 h-rows of v[h]*Wa[h][HDIM+k]
    int id = bid - 128;             // 0..63
    int c = id >> 2, kq = id & 3;   // c: h-chunk, kq: k-quarter
    int k = kq * 256 + threadIdx.x;
    int hb = c * 64;
    float acc = 0.f;
    #pragma unroll 8
    for (int i = 0; i < 64; ++i)
      acc += vvec[hb + i] * Wa[(size_t)(hb + i) * 2048 + HDIM + k];
    // accumulate per-chunk (4 k-quarters write disjoint k)
    ue_part[c * 1024 + k] = acc;
  }
}

// ===== L2: bid<64: gates GEMM (full K) + LSTM pointwise; else attention chunk
__global__ __launch_bounds__(256) void k_main(const float* __restrict__ enc,
                                              const float* __restrict__ ue_part,
                                              const float* __restrict__ W_ih,
                                              const float* __restrict__ W_hh,
                                              const float* __restrict__ b_ih,
                                              const float* __restrict__ b_hh,
                                              const float* __restrict__ c0,
                                              const short* __restrict__ xh,
                                              float* __restrict__ e_ws,
                                              float* __restrict__ ctx_part,
                                              float* __restrict__ ml_ws,
                                              float* __restrict__ out_h,
                                              float* __restrict__ out_c,
                                              short* __restrict__ xc) {
  __shared__ float smem[4160];
  int bid = blockIdx.x;
  int tid = threadIdx.x;
  int w = tid >> 6, lane = tid & 63;

  if (bid < 64) {
    // ---------------- gates GEMM: wave w = gate w, 16 h-rows, K=2048 --------
    int hbase = bid * 16;
    int r_lo = lane & 15, kq = (lane >> 4) * 8;
    int row = w * HDIM + hbase + r_lo;           // row of W_ih / W_hh
    const float* a0r = W_ih + (size_t)row * HDIM;
    const float* a1r = W_hh + (size_t)row * HDIM - HDIM;
    const short* x0 = xh + (size_t)(r_lo) * 2048;
    const short* x1 = xh + (size_t)(16 + r_lo) * 2048;
    const short* x2 = xh + (size_t)(32 + r_lo) * 2048;
    const short* x3 = xh + (size_t)(48 + r_lo) * 2048;
    f32x4 acc0 = {0,0,0,0}, acc1 = {0,0,0,0}, acc2 = {0,0,0,0}, acc3 = {0,0,0,0};
    #pragma unroll 4
    for (int k0 = 0; k0 < 2048; k0 += 32) {
      int k = k0 + kq;
      const float* ap = (k < HDIM) ? (a0r + k) : (a1r + k);
      f32x4 a0 = *(const f32x4*)ap;
      f32x4 a1 = *(const f32x4*)(ap + 4);
      bfx8 af;
      af[0] = f2bf(a0[0]); af[1] = f2bf(a0[1]); af[2] = f2bf(a0[2]); af[3] = f2bf(a0[3]);
      af[4] = f2bf(a1[0]); af[5] = f2bf(a1[1]); af[6] = f2bf(a1[2]); af[7] = f2bf(a1[3]);
      bfx8 b0 = *(const bfx8*)(x0 + k);
      bfx8 b1 = *(const bfx8*)(x1 + k);
      bfx8 b2 = *(const bfx8*)(x2 + k);
      bfx8 b3 = *(const bfx8*)(x3 + k);
      acc0 = __builtin_amdgcn_mfma_f32_16x16x32_bf16(af, b0, acc0, 0, 0, 0);
      acc1 = __builtin_amdgcn_mfma_f32_16x16x32_bf16(af, b1, acc1, 0, 0, 0);
      acc2 = __builtin_amdgcn_mfma_f32_16x16x32_bf16(af, b2, acc2, 0, 0, 0);
      acc3 = __builtin_amdgcn_mfma_f32_16x16x32_bf16(af, b3, acc3, 0, 0, 0);
    }
    // gbuf[gate][h_local][b] padded 65
    float* gbuf = smem;
    int hl4 = 4 * (lane >> 4);
    #pragma unroll
    for (int i = 0; i < 4; ++i) {
      gbuf[(w * 16 + hl4 + i) * 65 +  0 + r_lo] = acc0[i];
      gbuf[(w * 16 + hl4 + i) * 65 + 16 + r_lo] = acc1[i];
      gbuf[(w * 16 + hl4 + i) * 65 + 32 + r_lo] = acc2[i];
      gbuf[(w * 16 + hl4 + i) * 65 + 48 + r_lo] = acc3[i];
    }
    __syncthreads();
    // LSTM pointwise: 16 h x 64 b
    int hl = tid & 15, bq = tid >> 4;
    int hi = hbase + hl;
    float bi0 = b_ih[hi] + b_hh[hi];
    float bi1 = b_ih[HDIM + hi] + b_hh[HDIM + hi];
    float bi2 = b_ih[2 * HDIM + hi] + b_hh[2 * HDIM + hi];
    float bi3 = b_ih[3 * HDIM + hi] + b_hh[3 * HDIM + hi];
    #pragma unroll
    for (int u = 0; u < 4; ++u) {
      int b = bq + 16 * u;
      float gi = gbuf[( 0 + hl) * 65 + b] + bi0;
      float gf = gbuf[(16 + hl) * 65 + b] + bi1;
      float gg = gbuf[(32 + hl) * 65 + b] + bi2;
      float go = gbuf[(48 + hl) * 65 + b] + bi3;
      float cc = sigmf(gf) * c0[(size_t)b * HDIM + hi] + sigmf(gi) * tanhf(gg);
      float hh = sigmf(go) * tanhf(cc);
      out_h[(size_t)b * HDIM + hi] = hh;
      out_c[(size_t)b * HDIM + hi] = cc;
      xc[(size_t)b * 2048 + hi] = f2bf(hh);
    }
  } else {
    // ---------------- attention chunk: online softmax over 64 s-rows --------
    int ab = bid - 64;
    int b = ab & 63, ch = ab >> 6;
    f32x4 uev[4] = {{0,0,0,0},{0,0,0,0},{0,0,0,0},{0,0,0,0}};
    #pragma unroll
    for (int c = 0; c < 16; ++c) {
      #pragma unroll
      for (int j = 0; j < 4; ++j)
        uev[j] += *(const f32x4*)(ue_part + c * 1024 + j * 256 + lane * 4);
    }
    float m = -3.0e38f, l = 0.f;
    f32x4 cacc[4] = {{0,0,0,0},{0,0,0,0},{0,0,0,0},{0,0,0,0}};
    int sbase = ch * 64 + w * 16;
    for (int i = 0; i < 16; ++i) {
      int s = sbase + i;
      const float* ep = enc + ((size_t)s * BATCH + b) * HDIM;
      f32x4 ev[4];
      #pragma unroll
      for (int j = 0; j < 4; ++j) ev[j] = *(const f32x4*)(ep + j * 256 + lane * 4);
      float d = 0.f;
      #pragma unroll
      for (int j = 0; j < 4; ++j)
        d += ev[j][0]*uev[j][0] + ev[j][1]*uev[j][1] + ev[j][2]*uev[j][2] + ev[j][3]*uev[j][3];
      #pragma unroll
      for (int off = 32; off >= 1; off >>= 1) d += __shfl_xor(d, off);
      if (lane == 0) e_ws[(size_t)b * S_LEN + s] = d;
      float mn = fmaxf(m, d);
      float sc = __expf(m - mn);
      float p  = __expf(d - mn);
      l = l * sc + p;
      #pragma unroll
      for (int j = 0; j < 4; ++j) cacc[j] = cacc[j] * sc + p * ev[j];
      m = mn;
    }
    float* ls_ctx = smem;          // [4][1024]
    float* ls_m   = smem + 4096;   // [4]
    float* ls_l   = smem + 4100;   // [4]
    #pragma unroll
    for (int j = 0; j < 4; ++j)
      *(f32x4*)&ls_ctx[w * 1024 + j * 256 + lane * 4] = cacc[j];
    if (lane == 0) { ls_m[w] = m; ls_l[w] = l; }
    __syncthreads();
    float mb = fmaxf(fmaxf(ls_m[0], ls_m[1]), fmaxf(ls_m[2], ls_m[3]));
    float f0 = __expf(ls_m[0] - mb), f1 = __expf(ls_m[1] - mb);
    float f2 = __expf(ls_m[2] - mb), f3 = __expf(ls_m[3] - mb);
    float lb = ls_l[0]*f0 + ls_l[1]*f1 + ls_l[2]*f2 + ls_l[3]*f3;
    int h = tid * 4;
    f32x4 v0 = *(f32x4*)&ls_ctx[0 * 1024 + h];
    f32x4 v1 = *(f32x4*)&ls_ctx[1 * 1024 + h];
    f32x4 v2 = *(f32x4*)&ls_ctx[2 * 1024 + h];
    f32x4 v3 = *(f32x4*)&ls_ctx[3 * 1024 + h];
    f32x4 sum = f0*v0 + f1*v1 + f2*v2 + f3*v3;
    *(f32x4*)(ctx_part + (size_t)(b * 16 + ch) * HDIM + h) = sum;
    if (tid == 0) {
      ml_ws[(b * 16 + ch) * 2 + 0] = mb;
      ml_ws[(b * 16 + ch) * 2 + 1] = lb;
    }
  }
}

// ===== L3: combine chunk partials -> attn out + ctx bf16 into xc[H:]
__global__ __launch_bounds__(256) void k_attn_comb(const float* __restrict__ e_ws,
                                                   const float* __restrict__ ctx_part,
                                                   const float* __restrict__ ml_ws,
                                                   float* __restrict__ attn_out,
                                                   short* __restrict__ xc) {
  int b = blockIdx.x;
  float mc[16], lc[16], fc[16];
  float mb = -3.0e38f;
  #pragma unroll
  for (int c = 0; c < 16; ++c) {
    mc[c] = ml_ws[(b * 16 + c) * 2 + 0];
    lc[c] = ml_ws[(b * 16 + c) * 2 + 1];
    mb = fmaxf(mb, mc[c]);
  }
  float L = 0.f;
  #pragma unroll
  for (int c = 0; c < 16; ++c) { fc[c] = __expf(mc[c] - mb); L += lc[c] * fc[c]; }
  float invL = 1.f / L;
  int h = threadIdx.x * 4;
  f32x4 sum = {0,0,0,0};
  #pragma unroll
  for (int c = 0; c < 16; ++c) {
    f32x4 vv = *(const f32x4*)(ctx_part + (size_t)(b * 16 + c) * HDIM + h);
    sum += fc[c] * vv;
  }
  sum *= invL;
  bfx4 o;
  o[0] = f2bf(sum[0]); o[1] = f2bf(sum[1]); o[2] = f2bf(sum[2]); o[3] = f2bf(sum[3]);
  *(bfx4*)(xc + (size_t)b * 2048 + HDIM + h) = o;
  int s = threadIdx.x * 4;
  f32x4 ev = *(const f32x4*)(e_ws + (size_t)b * S_LEN + s);
  f32x4 a;
  a[0] = __expf(ev[0] - mb) * invL; a[1] = __expf(ev[1] - mb) * invL;
  a[2] = __expf(ev[2] - mb) * invL; a[3] = __expf(ev[3] - mb) * invL;
  *(f32x4*)(attn_out + (size_t)b * S_LEN + s) = a;
}

// ===== L4: tmp = tanh(Wal @ xc + bal) -> bf16 (full K per block, LDS reduce)
__global__ __launch_bounds__(256) void k_wal(const float* __restrict__ Wal,
                                             const float* __restrict__ bal,
                                             const short* __restrict__ xc,
                                             short* __restrict__ tmpb) {
  __shared__ float wbuf[4 * 16 * 65];
  int tid = threadIdx.x;
  int w = tid >> 6, lane = tid & 63;
  int r_lo = lane & 15, kq = (lane >> 4) * 8;
  int tile = blockIdx.x;                        // 0..63
  int row = tile * 16 + r_lo;
  const float* ar = Wal + (size_t)row * 2048;
  const short* x0 = xc + (size_t)(r_lo) * 2048;
  const short* x1 = xc + (size_t)(16 + r_lo) * 2048;
  const short* x2 = xc + (size_t)(32 + r_lo) * 2048;
  const short* x3 = xc + (size_t)(48 + r_lo) * 2048;
  f32x4 acc0 = {0,0,0,0}, acc1 = {0,0,0,0}, acc2 = {0,0,0,0}, acc3 = {0,0,0,0};
  int kbeg = w * 512;
  #pragma unroll 4
  for (int k0 = kbeg; k0 < kbeg + 512; k0 += 32) {
    int k = k0 + kq;
    f32x4 a0 = *(const f32x4*)(ar + k);
    f32x4 a1 = *(const f32x4*)(ar + k + 4);
    bfx8 af;
    af[0] = f2bf(a0[0]); af[1] = f2bf(a0[1]); af[2] = f2bf(a0[2]); af[3] = f2bf(a0[3]);
    af[4] = f2bf(a1[0]); af[5] = f2bf(a1[1]); af[6] = f2bf(a1[2]); af[7] = f2bf(a1[3]);
    bfx8 b0 = *(const bfx8*)(x0 + k);
    bfx8 b1 = *(const bfx8*)(x1 + k);
    bfx8 b2 = *(const bfx8*)(x2 + k);
    bfx8 b3 = *(const bfx8*)(x3 + k);
    acc0 = __builtin_amdgcn_mfma_f32_16x16x32_bf16(af, b0, acc0, 0, 0, 0);
    acc1 = __builtin_amdgcn_mfma_f32_16x16x32_bf16(af, b1, acc1, 0, 0, 0);
    acc2 = __builtin_amdgcn_mfma_f32_16x16x32_bf16(af, b2, acc2, 0, 0, 0);
    acc3 = __builtin_amdgcn_mfma_f32_16x16x32_bf16(af, b3, acc3, 0, 0, 0);
  }
  int hl4 = 4 * (lane >> 4);
  #pragma unroll
  for (int i = 0; i < 4; ++i) {
    wbuf[(w * 16 + hl4 + i) * 65 +  0 + r_lo] = acc0[i];
    wbuf[(w * 16 + hl4 + i) * 65 + 16 + r_lo] = acc1[i];
    wbuf[(w * 16 + hl4 + i) * 65 + 32 + r_lo] = acc2[i];
    wbuf[(w * 16 + hl4 + i) * 65 + 48 + r_lo] = acc3[i];
  }
  __syncthreads();
  int hl = tid & 15, bq = tid >> 4;
  float bb = bal[tile * 16 + hl];
  #pragma unroll
  for (int u = 0; u < 4; ++u) {
    int b = bq + 16 * u;
    float s = wbuf[(0 * 16 + hl) * 65 + b] + wbuf[(1 * 16 + hl) * 65 + b]
            + wbuf[(2 * 16 + hl) * 65 + b] + wbuf[(3 * 16 + hl) * 65 + b];
    tmpb[(size_t)b * HDIM + tile * 16 + hl] = f2bf(tanhf(s + bb));
  }
}

// ===== L5: logits = tmp @ Wout^T + bout  (32 rows/block, 2 waves)
__global__ __launch_bounds__(128) void k_logits(const float* __restrict__ Wout,
                                                const short* __restrict__ tmpb,
                                                const float* __restrict__ bout,
                                                float* __restrict__ out) {
  __shared__ float lt[64 * 33];
  int tid = threadIdx.x;
  int w = tid >> 6, lane = tid & 63;
  int r_lo = lane & 15, kq = (lane >> 4) * 8;
  int v0 = blockIdx.x * 32;
  int row = v0 + w * 16 + r_lo;
  if (row >= VOCAB) row = VOCAB - 1;
  const float* ar = Wout + (size_t)row * HDIM;
  const short* x0 = tmpb + (size_t)(r_lo) * HDIM;
  const short* x1 = tmpb + (size_t)(16 + r_lo) * HDIM;
  const short* x2 = tmpb + (size_t)(32 + r_lo) * HDIM;
  const short* x3 = tmpb + (size_t)(48 + r_lo) * HDIM;
  f32x4 acc0 = {0,0,0,0}, acc1 = {0,0,0,0}, acc2 = {0,0,0,0}, acc3 = {0,0,0,0};
  #pragma unroll 4
  for (int k0 = 0; k0 < HDIM; k0 += 32) {
    int k = k0 + kq;
    f32x4 a0 = *(const f32x4*)(ar + k);
    f32x4 a1 = *(const f32x4*)(ar + k + 4);
    bfx8 af;
    af[0] = f2bf(a0[0]); af[1] = f2bf(a0[1]); af[2] = f2bf(a0[2]); af[3] = f2bf(a0[3]);
    af[4] = f2bf(a1[0]); af[5] = f2bf(a1[1]); af[6] = f2bf(a1[2]); af[7] = f2bf(a1[3]);
    bfx8 b0 = *(const bfx8*)(x0 + k);
    bfx8 b1 = *(const bfx8*)(x1 + k);
    bfx8 b2 = *(const bfx8*)(x2 + k);
    bfx8 b3 = *(const bfx8*)(x3 + k);
    acc0 = __builtin_amdgcn_mfma_f32_16x16x32_bf16(af, b0, acc0, 0, 0, 0);
    acc1 = __builtin_amdgcn_mfma_f32_16x16x32_bf16(af, b1, acc1, 0, 0, 0);
    acc2 = __builtin_amdgcn_mfma_f32_16x16x32_bf16(af, b2, acc2, 0, 0, 0);
    acc3 = __builtin_amdgcn_mfma_f32_16x16x32_bf16(af, b3, acc3, 0, 0, 0);
  }
  int vl4 = w * 16 + 4 * (lane >> 4);
  #pragma unroll
  for (int i = 0; i < 4; ++i) {
    lt[( 0 + r_lo) * 33 + vl4 + i] = acc0[i];
    lt[(16 + r_lo) * 33 + vl4 + i] = acc1[i];
    lt[(32 + r_lo) * 33 + vl4 + i] = acc2[i];
    lt[(48 + r_lo) * 33 + vl4 + i] = acc3[i];
  }
  __syncthreads();
  int vloc = tid & 31, bq = tid >> 5;   // bq 0..3
  int v = v0 + vloc;
  if (v < VOCAB) {
    float bo = bout[v];
    #pragma unroll
    for (int q = 0; q < 16; ++q) {
      int b = bq * 16 + q;
      out[(size_t)b * VOCAB + v] = lt[b * 33 + vloc] + bo;
    }
  }
}

extern "C" void kernel_launch(void* const* d_in, const int* in_sizes, int n_in,
                              void* d_out, int out_size, void* d_ws, size_t ws_size,
                              hipStream_t stream) {
  const float* enc   = (const float*)d_in[0];
  const int*   seq   = (const int*)  d_in[1];
  const float* h0    = (const float*)d_in[2];
  const float* c0    = (const float*)d_in[3];
  const float* embed = (const float*)d_in[4];
  const float* W_ih  = (const float*)d_in[5];
  const float* W_hh  = (const float*)d_in[6];
  const float* b_ih  = (const float*)d_in[7];
  const float* b_hh  = (const float*)d_in[8];
  const float* Wa    = (const float*)d_in[9];
  // d_in[10] = ba: cancels in softmax, unused
  const float* vvec  = (const float*)d_in[11];
  const float* Wal   = (const float*)d_in[12];
  const float* bal   = (const float*)d_in[13];
  const float* Wout  = (const float*)d_in[14];
  const float* bout  = (const float*)d_in[15];

  float* out        = (float*)d_out;
  float* out_h      = out + (size_t)BATCH * VOCAB;
  float* out_c      = out_h + BATCH * HDIM;
  float* out_attn   = out_c + BATCH * HDIM;

  float* ws         = (float*)d_ws;
  float* ue_part    = ws;                          // 16*1024
  float* e_ws       = ue_part + 16 * 1024;         // 64*1024
  float* ml_ws      = e_ws + 64 * 1024;            // 2048
  float* ctx_part   = ml_ws + 2048;                // 64*16*1024
  short* xh         = (short*)(ctx_part + 64 * 16 * 1024);  // 64*2048 bf16
  short* xc         = xh + 64 * 2048;              // 64*2048 bf16
  short* tmpb       = xc + 64 * 2048;              // 64*1024 bf16

  k_prep<<<192, 256, 0, stream>>>(seq, embed, h0, Wa, vvec, xh, ue_part);
  k_main<<<1088, 256, 0, stream>>>(enc, ue_part, W_ih, W_hh, b_ih, b_hh, c0, xh,
                                   e_ws, ctx_part, ml_ws, out_h, out_c, xc);
  k_attn_comb<<<64, 256, 0, stream>>>(e_ws, ctx_part, ml_ws, out_attn, xc);
  k_wal<<<64, 256, 0, stream>>>(Wal, bal, xc, tmpb);
  k_logits<<<1571, 128, 0, stream>>>(Wout, tmpb, bout, out);
}